// Round 1
// baseline (2023.658 us; speedup 1.0000x reference)
//
#include <hip/hip_runtime.h>
#include <hip/hip_bf16.h>

// Problem constants
#define LNUM 6
#define HNUM 16
#define DMODEL 768
#define FFDIM 3072
#define BATCH 4
#define NTOK 1023
#define SEQ 1024          // NTOK + 1
#define HD 48             // DMODEL / HNUM
#define EPS 1e-5f

typedef __hip_bfloat16 bf16;

__device__ __forceinline__ unsigned short f2bf_raw(float f) {
  bf16 h = __float2bfloat16(f);
  union { bf16 h; unsigned short s; } u; u.h = h; return u.s;
}
__device__ __forceinline__ float bflo(unsigned int u) { return __uint_as_float(u << 16); }
__device__ __forceinline__ float bfhi(unsigned int u) { return __uint_as_float(u & 0xffff0000u); }

// DPP helpers: reduction across the 16 contiguous lanes of a DPP "row".
// quad_perm(1,0,3,2)=0xB1 (xor1), quad_perm(2,3,0,1)=0x4E (xor2),
// row_ror:4=0x124, row_ror:8=0x128.
template <int CTRL>
__device__ __forceinline__ float dppf(float x) {
  return __int_as_float(__builtin_amdgcn_update_dpp(
      0, __float_as_int(x), CTRL, 0xf, 0xf, true));
}
__device__ __forceinline__ float row_max16(float x) {
  x = fmaxf(x, dppf<0xB1>(x));
  x = fmaxf(x, dppf<0x4E>(x));
  x = fmaxf(x, dppf<0x124>(x));
  x = fmaxf(x, dppf<0x128>(x));
  return x;
}
__device__ __forceinline__ float row_sum16(float x) {
  x += dppf<0xB1>(x);
  x += dppf<0x4E>(x);
  x += dppf<0x124>(x);
  x += dppf<0x128>(x);
  return x;
}

// ---------------------------------------------------------------------------
// concat: x[b,s,:] = s==0 ? cls_token : cls_tokens[b,s-1,:]  (fp32 residual)
// ---------------------------------------------------------------------------
__global__ __launch_bounds__(256) void concat_kernel(
    const float* __restrict__ cls_tokens, const float* __restrict__ cls_token,
    float* __restrict__ x) {
  size_t i = (size_t)blockIdx.x * blockDim.x + threadIdx.x;
  const size_t total = (size_t)BATCH * SEQ * DMODEL;
  if (i >= total) return;
  int d = (int)(i % DMODEL);
  size_t bs = i / DMODEL;
  int s = (int)(bs % SEQ);
  int b = (int)(bs / SEQ);
  float v;
  if (s == 0) v = cls_token[d];
  else v = cls_tokens[((size_t)b * NTOK + (s - 1)) * DMODEL + d];
  x[i] = v;
}

// ---------------------------------------------------------------------------
// per-layer weight pack fp32 -> bf16 (Wqkv | Wo | Wg | Wu | Wd concatenated)
// ---------------------------------------------------------------------------
#define W_QKV4  442368
#define W_O4    147456
#define W_FF4   589824
__global__ __launch_bounds__(256) void convert_w_kernel(
    const float* __restrict__ wqkv, const float* __restrict__ wo,
    const float* __restrict__ wg, const float* __restrict__ wu,
    const float* __restrict__ wd, bf16* __restrict__ dst) {
  size_t i4 = (size_t)blockIdx.x * 256 + threadIdx.x;
  size_t off4 = i4;
  const float* src;
  if (off4 < W_QKV4) src = wqkv;
  else { off4 -= W_QKV4;
    if (off4 < W_O4) src = wo;
    else { off4 -= W_O4;
      if (off4 < W_FF4) src = wg;
      else { off4 -= W_FF4;
        if (off4 < W_FF4) src = wu;
        else { off4 -= W_FF4; src = wd; } } } }
  float4 v = ((const float4*)src)[off4];
  ushort4 o;
  o.x = f2bf_raw(v.x); o.y = f2bf_raw(v.y);
  o.z = f2bf_raw(v.z); o.w = f2bf_raw(v.w);
  ((ushort4*)dst)[i4] = o;
}

// ---------------------------------------------------------------------------
// layernorm: one 256-thread block per row of 768. OUT = float or bf16.
// ---------------------------------------------------------------------------
__device__ __forceinline__ void st_ln(float* p, float v) { *p = v; }
__device__ __forceinline__ void st_ln(bf16* p, float v) { *p = __float2bfloat16(v); }

template <typename OUT>
__global__ __launch_bounds__(256) void ln_kernel(
    const float* __restrict__ in, OUT* __restrict__ out,
    const float* __restrict__ w, const float* __restrict__ bias,
    size_t in_stride, size_t out_stride) {
  const int row = blockIdx.x;
  const int tid = threadIdx.x;
  const float* x = in + (size_t)row * in_stride;
  OUT* y = out + (size_t)row * out_stride;

  float v0 = x[tid], v1 = x[tid + 256], v2 = x[tid + 512];
  float s = v0 + v1 + v2;
  float sq = v0 * v0 + v1 * v1 + v2 * v2;

  __shared__ float s_sum[256];
  __shared__ float s_sq[256];
  s_sum[tid] = s;
  s_sq[tid] = sq;
  __syncthreads();
  for (int off = 128; off > 0; off >>= 1) {
    if (tid < off) {
      s_sum[tid] += s_sum[tid + off];
      s_sq[tid] += s_sq[tid + off];
    }
    __syncthreads();
  }
  const float inv_d = 1.0f / (float)DMODEL;
  float mean = s_sum[0] * inv_d;
  float var = s_sq[0] * inv_d - mean * mean;
  float rstd = rsqrtf(var + EPS);

  st_ln(y + tid,       (v0 - mean) * rstd * w[tid]       + bias[tid]);
  st_ln(y + tid + 256, (v1 - mean) * rstd * w[tid + 256] + bias[tid + 256]);
  st_ln(y + tid + 512, (v2 - mean) * rstd * w[tid + 512] + bias[tid + 512]);
}

// ---------------------------------------------------------------------------
// bf16 MFMA NT GEMM, double-buffered LDS pipeline. 128x128 tile, BK=32.
// CMODE: 0 = store fp32, 1 = accumulate fp32, 2 = store bf16.
// ---------------------------------------------------------------------------
#define BM 128
#define BN 128
#define BK 32

typedef __attribute__((ext_vector_type(8))) short bfrag;
typedef __attribute__((ext_vector_type(4))) float f32x4;

__device__ __forceinline__ void async_copy16(const void* g, void* l) {
  __builtin_amdgcn_global_load_lds(
      (const __attribute__((address_space(1))) void*)g,
      (__attribute__((address_space(3))) void*)l, 16, 0, 0);
}

template <int CMODE>
__global__ __launch_bounds__(256) void gemm_bf16(
    const bf16* __restrict__ A, const bf16* __restrict__ B,
    void* __restrict__ Cv, int M, int N, int K) {
  __shared__ bf16 As[2][BM][BK];  // 16 KB
  __shared__ bf16 Bs[2][BN][BK];  // 16 KB

  const int tid = threadIdx.x;
  const int wave = tid >> 6;
  const int lane = tid & 63;
  const int m0 = blockIdx.y * BM;
  const int n0 = blockIdx.x * BN;
  const int wm = (wave & 1) * 64;
  const int wn = (wave >> 1) * 64;

  f32x4 acc[4][4];
#pragma unroll
  for (int i = 0; i < 4; i++)
#pragma unroll
    for (int j = 0; j < 4; j++) acc[i][j] = (f32x4)(0.f);

  const int lrow = lane >> 2;
  const int lcol = (lane & 3) * 8;
  const bf16* Ag[2]; const bf16* Bg[2];
  void *AsB[2][2], *BsB[2][2];   // [buf][chunk]
#pragma unroll
  for (int j = 0; j < 2; j++) {
    int c = j * 4 + wave;
    Ag[j] = A + (size_t)(m0 + c * 16 + lrow) * K + lcol;
    Bg[j] = B + (size_t)(n0 + c * 16 + lrow) * K + lcol;
#pragma unroll
    for (int bf = 0; bf < 2; bf++) {
      AsB[bf][j] = (void*)&As[bf][c * 16][0];
      BsB[bf][j] = (void*)&Bs[bf][c * 16][0];
    }
  }

#pragma unroll
  for (int j = 0; j < 2; j++) {
    async_copy16(Ag[j], AsB[0][j]);
    async_copy16(Bg[j], BsB[0][j]);
  }

  const int fr = lane & 15;
  const int fk = (lane >> 4) * 8;
  const int nk = K / BK;

  for (int ki = 0; ki < nk; ki++) {
    const int cur = ki & 1;
    __syncthreads();
    if (ki + 1 < nk) {
      const int k0 = (ki + 1) * BK;
#pragma unroll
      for (int j = 0; j < 2; j++) {
        async_copy16(Ag[j] + k0, AsB[cur ^ 1][j]);
        async_copy16(Bg[j] + k0, BsB[cur ^ 1][j]);
      }
    }
    bfrag a[4], b[4];
#pragma unroll
    for (int i = 0; i < 4; i++) {
      a[i] = *(const bfrag*)&As[cur][wm + i * 16 + fr][fk];
      b[i] = *(const bfrag*)&Bs[cur][wn + i * 16 + fr][fk];
    }
#pragma unroll
    for (int i = 0; i < 4; i++)
#pragma unroll
      for (int j = 0; j < 4; j++)
        acc[i][j] = __builtin_amdgcn_mfma_f32_16x16x32_bf16(a[i], b[j], acc[i][j], 0, 0, 0);
  }

  const int ccol = lane & 15;
  const int crow = (lane >> 4) * 4;
#pragma unroll
  for (int i = 0; i < 4; i++) {
#pragma unroll
    for (int j = 0; j < 4; j++) {
#pragma unroll
      for (int r = 0; r < 4; r++) {
        const size_t gm = m0 + wm + i * 16 + crow + r;
        const size_t gn = n0 + wn + j * 16 + ccol;
        if (CMODE == 2) {
          ((bf16*)Cv)[gm * N + gn] = __float2bfloat16(acc[i][j][r]);
        } else if (CMODE == 1) {
          float* cp = (float*)Cv + gm * N + gn;
          *cp += acc[i][j][r];
        } else {
          ((float*)Cv)[gm * N + gn] = acc[i][j][r];
        }
      }
    }
  }
}

// ---------------------------------------------------------------------------
// BN=64 variant for N=768 GEMMs (wo, wd): grid 384 blocks -> full CU coverage.
// 128x64 tile; waves 2x2, each 64x32 subtile (acc[4][2]).
// ---------------------------------------------------------------------------
template <int CMODE>
__global__ __launch_bounds__(256) void gemm_bf16_n64(
    const bf16* __restrict__ A, const bf16* __restrict__ B,
    void* __restrict__ Cv, int M, int N, int K) {
  __shared__ bf16 As[2][BM][BK];  // 16 KB
  __shared__ bf16 Bs[2][64][BK];  // 8 KB

  const int tid = threadIdx.x;
  const int wave = tid >> 6;
  const int lane = tid & 63;
  const int m0 = blockIdx.y * BM;
  const int n0 = blockIdx.x * 64;
  const int wm = (wave & 1) * 64;
  const int wn = (wave >> 1) * 32;

  f32x4 acc[4][2];
#pragma unroll
  for (int i = 0; i < 4; i++)
#pragma unroll
    for (int j = 0; j < 2; j++) acc[i][j] = (f32x4)(0.f);

  const int lrow = lane >> 2;
  const int lcol = (lane & 3) * 8;
  const bf16* Ag[2]; const bf16* Bg;
  void *AsB[2][2], *BsB[2];
#pragma unroll
  for (int j = 0; j < 2; j++) {
    int c = j * 4 + wave;
    Ag[j] = A + (size_t)(m0 + c * 16 + lrow) * K + lcol;
#pragma unroll
    for (int bf = 0; bf < 2; bf++) AsB[bf][j] = (void*)&As[bf][c * 16][0];
  }
  Bg = B + (size_t)(n0 + wave * 16 + lrow) * K + lcol;
#pragma unroll
  for (int bf = 0; bf < 2; bf++) BsB[bf] = (void*)&Bs[bf][wave * 16][0];

  async_copy16(Ag[0], AsB[0][0]);
  async_copy16(Ag[1], AsB[0][1]);
  async_copy16(Bg, BsB[0]);

  const int fr = lane & 15;
  const int fk = (lane >> 4) * 8;
  const int nk = K / BK;

  for (int ki = 0; ki < nk; ki++) {
    const int cur = ki & 1;
    __syncthreads();
    if (ki + 1 < nk) {
      const int k0 = (ki + 1) * BK;
      async_copy16(Ag[0] + k0, AsB[cur ^ 1][0]);
      async_copy16(Ag[1] + k0, AsB[cur ^ 1][1]);
      async_copy16(Bg + k0, BsB[cur ^ 1]);
    }
    bfrag a[4], b[2];
#pragma unroll
    for (int i = 0; i < 4; i++)
      a[i] = *(const bfrag*)&As[cur][wm + i * 16 + fr][fk];
#pragma unroll
    for (int j = 0; j < 2; j++)
      b[j] = *(const bfrag*)&Bs[cur][wn + j * 16 + fr][fk];
#pragma unroll
    for (int i = 0; i < 4; i++)
#pragma unroll
      for (int j = 0; j < 2; j++)
        acc[i][j] = __builtin_amdgcn_mfma_f32_16x16x32_bf16(a[i], b[j], acc[i][j], 0, 0, 0);
  }

  const int ccol = lane & 15;
  const int crow = (lane >> 4) * 4;
#pragma unroll
  for (int i = 0; i < 4; i++) {
#pragma unroll
    for (int j = 0; j < 2; j++) {
#pragma unroll
      for (int r = 0; r < 4; r++) {
        const size_t gm = m0 + wm + i * 16 + crow + r;
        const size_t gn = n0 + wn + j * 16 + ccol;
        if (CMODE == 2) {
          ((bf16*)Cv)[gm * N + gn] = __float2bfloat16(acc[i][j][r]);
        } else if (CMODE == 1) {
          float* cp = (float*)Cv + gm * N + gn;
          *cp += acc[i][j][r];
        } else {
          ((float*)Cv)[gm * N + gn] = acc[i][j][r];
        }
      }
    }
  }
}

// ---------------------------------------------------------------------------
// Fused gate+up GEMM with silu epilogue (dbuf, 3 staged matrices).
// ---------------------------------------------------------------------------
__global__ __launch_bounds__(256) void gemm_gateup(
    const bf16* __restrict__ A, const bf16* __restrict__ Wg,
    const bf16* __restrict__ Wu, bf16* __restrict__ gu, int M, int N, int K) {
  __shared__ bf16 As[2][BM][BK];
  __shared__ bf16 Gs[2][BN][BK];
  __shared__ bf16 Us[2][BN][BK];

  const int tid = threadIdx.x;
  const int wave = tid >> 6;
  const int lane = tid & 63;
  const int m0 = blockIdx.y * BM;
  const int n0 = blockIdx.x * BN;
  const int wm = (wave & 1) * 64;
  const int wn = (wave >> 1) * 64;

  f32x4 accG[4][4], accU[4][4];
#pragma unroll
  for (int i = 0; i < 4; i++)
#pragma unroll
    for (int j = 0; j < 4; j++) { accG[i][j] = (f32x4)(0.f); accU[i][j] = (f32x4)(0.f); }

  const int lrow = lane >> 2;
  const int lcol = (lane & 3) * 8;
  const bf16 *Ag[2], *Gg[2], *Ug[2];
  void *AsB[2][2], *GsB[2][2], *UsB[2][2];
#pragma unroll
  for (int j = 0; j < 2; j++) {
    int c = j * 4 + wave;
    Ag[j] = A + (size_t)(m0 + c * 16 + lrow) * K + lcol;
    Gg[j] = Wg + (size_t)(n0 + c * 16 + lrow) * K + lcol;
    Ug[j] = Wu + (size_t)(n0 + c * 16 + lrow) * K + lcol;
#pragma unroll
    for (int bf = 0; bf < 2; bf++) {
      AsB[bf][j] = (void*)&As[bf][c * 16][0];
      GsB[bf][j] = (void*)&Gs[bf][c * 16][0];
      UsB[bf][j] = (void*)&Us[bf][c * 16][0];
    }
  }

#pragma unroll
  for (int j = 0; j < 2; j++) {
    async_copy16(Ag[j], AsB[0][j]);
    async_copy16(Gg[j], GsB[0][j]);
    async_copy16(Ug[j], UsB[0][j]);
  }

  const int fr = lane & 15;
  const int fk = (lane >> 4) * 8;
  const int nk = K / BK;

  for (int ki = 0; ki < nk; ki++) {
    const int cur = ki & 1;
    __syncthreads();
    if (ki + 1 < nk) {
      const int k0 = (ki + 1) * BK;
#pragma unroll
      for (int j = 0; j < 2; j++) {
        async_copy16(Ag[j] + k0, AsB[cur ^ 1][j]);
        async_copy16(Gg[j] + k0, GsB[cur ^ 1][j]);
        async_copy16(Ug[j] + k0, UsB[cur ^ 1][j]);
      }
    }
    bfrag a[4], g[4], u[4];
#pragma unroll
    for (int i = 0; i < 4; i++) {
      a[i] = *(const bfrag*)&As[cur][wm + i * 16 + fr][fk];
      g[i] = *(const bfrag*)&Gs[cur][wn + i * 16 + fr][fk];
      u[i] = *(const bfrag*)&Us[cur][wn + i * 16 + fr][fk];
    }
#pragma unroll
    for (int i = 0; i < 4; i++)
#pragma unroll
      for (int j = 0; j < 4; j++) {
        accG[i][j] = __builtin_amdgcn_mfma_f32_16x16x32_bf16(a[i], g[j], accG[i][j], 0, 0, 0);
        accU[i][j] = __builtin_amdgcn_mfma_f32_16x16x32_bf16(a[i], u[j], accU[i][j], 0, 0, 0);
      }
  }

  const int ccol = lane & 15;
  const int crow = (lane >> 4) * 4;
#pragma unroll
  for (int i = 0; i < 4; i++) {
#pragma unroll
    for (int j = 0; j < 4; j++) {
#pragma unroll
      for (int r = 0; r < 4; r++) {
        const size_t gm = m0 + wm + i * 16 + crow + r;
        const size_t gn = n0 + wn + j * 16 + ccol;
        const float gv = accG[i][j][r];
        const float uv = accU[i][j][r];
        const float res = gv / (1.0f + __expf(-gv)) * uv;
        gu[gm * N + gn] = __float2bfloat16(res);
      }
    }
  }
}

// ---------------------------------------------------------------------------
// V transpose pre-pass: vt[b][h][d][s] = qkv[b][s][2D + h*HD + d]
// One block per (64-key tile, h, b); LDS-tiled, conflict-free interleave.
// ---------------------------------------------------------------------------
__global__ __launch_bounds__(256) void transpose_v(
    const bf16* __restrict__ qkv, bf16* __restrict__ vt) {
  __shared__ bf16 T[HD][64];
  const int tid = threadIdx.x;
  const int kb = blockIdx.x * 64;
  const int h = blockIdx.y;
  const int b = blockIdx.z;
  const size_t rstride = 3 * DMODEL;
  const bf16* vsrc = qkv + ((size_t)(b * SEQ + kb)) * rstride + 2 * DMODEL + h * HD;

  if (tid < 192) {
    int p = tid & 31, c = tid >> 5;   // 32 key-pairs x 6 d-chunks
    const bf16* v0 = vsrc + (size_t)(2 * p) * rstride + c * 8;
    uint4 r0 = *(const uint4*)v0;
    uint4 r1 = *(const uint4*)(v0 + rstride);
    const unsigned int* w0 = (const unsigned int*)&r0;
    const unsigned int* w1 = (const unsigned int*)&r1;
#pragma unroll
    for (int i = 0; i < 8; i++) {
      unsigned int lo = (i & 1) ? (w0[i >> 1] >> 16) : (w0[i >> 1] & 0xffffu);
      unsigned int hi = (i & 1) ? (w1[i >> 1] >> 16) : (w1[i >> 1] & 0xffffu);
      *(unsigned int*)&T[c * 8 + i][2 * p] = lo | (hi << 16);
    }
  }
  __syncthreads();
  for (int it = tid; it < HD * 8; it += 256) {
    int d = it >> 3, c = it & 7;
    *(uint4*)(vt + ((size_t)((b * HNUM + h) * HD + d)) * SEQ + kb + c * 8) =
        *(const uint4*)&T[d][c * 8];
  }
}

// ---------------------------------------------------------------------------
// MFMA flash attention — barrier-free register-streaming version.
//
// Per wave: Q (prescaled by 1/sqrt(48)*log2e) held in 2 register fragments
// (zeroed for d>=48 => the K-side pad garbage multiplies by zero inside the
// MFMA). K and V fragments are loaded straight from global (L2-resident;
// the 4 waves of a block share the same (b,h) K/V tiles via L1). K is
// register-double-buffered one tile ahead (A/B named sets, static indexing);
// V is issued at tile start and consumed ~400+ cycles later in PV.
// Softmax: DPP row reductions (no ds_bpermute), exp2 domain.
// Only LDS: wave-private P buffer (no __syncthreads anywhere).
// Grid: flat 1024, XCD-swizzled so each XCD owns 8 whole (b,h) pairs.
// ---------------------------------------------------------------------------
#define AQT 64
#define AKT 64

#define ATTN_TILE(KCUR, KNXT, KB)                                              \
  {                                                                            \
    const int kb = (KB);                                                       \
    bfrag vf[2][3];                                                            \
    _Pragma("unroll") for (int ks = 0; ks < 2; ks++)                           \
      _Pragma("unroll") for (int t = 0; t < 3; t++)                            \
        vf[ks][t] = *(const bfrag*)(vl + (size_t)(t * 16) * SEQ + kb + ks * 32); \
    if (kb + AKT < SEQ) {                                                      \
      _Pragma("unroll") for (int ks = 0; ks < 2; ks++)                         \
        _Pragma("unroll") for (int j = 0; j < 4; j++)                          \
          KNXT[ks][j] =                                                        \
              *(const bfrag*)(kl + (size_t)(kb + AKT + j * 16) * rstride + ks * 32); \
    }                                                                          \
    f32x4 accS[4];                                                             \
    _Pragma("unroll") for (int j = 0; j < 4; j++) accS[j] = (f32x4)(0.f);      \
    __builtin_amdgcn_s_setprio(1);                                             \
    _Pragma("unroll") for (int ks = 0; ks < 2; ks++)                           \
      _Pragma("unroll") for (int j = 0; j < 4; j++)                            \
        accS[j] = __builtin_amdgcn_mfma_f32_16x16x32_bf16(aq[ks], KCUR[ks][j], \
                                                          accS[j], 0, 0, 0);  \
    __builtin_amdgcn_s_setprio(0);                                             \
    _Pragma("unroll") for (int r = 0; r < 4; r++) {                            \
      const float fq = (float)(qb + wq * 16 + lh * 4 + r);                     \
      float s0 = accS[0][r] - slope * fabsf(fq - (float)(kb + l15));           \
      float s1 = accS[1][r] - slope * fabsf(fq - (float)(kb + 16 + l15));      \
      float s2 = accS[2][r] - slope * fabsf(fq - (float)(kb + 32 + l15));      \
      float s3 = accS[3][r] - slope * fabsf(fq - (float)(kb + 48 + l15));      \
      float mx = row_max16(fmaxf(fmaxf(s0, s1), fmaxf(s2, s3)));               \
      const float mnew = fmaxf(m_[r], mx);                                     \
      const float corr = exp2f(m_[r] - mnew);                                  \
      const float p0 = exp2f(s0 - mnew), p1 = exp2f(s1 - mnew);                \
      const float p2 = exp2f(s2 - mnew), p3 = exp2f(s3 - mnew);                \
      const float rs = row_sum16((p0 + p1) + (p2 + p3));                       \
      l_[r] = l_[r] * corr + rs;                                               \
      m_[r] = mnew;                                                            \
      accO[0][r] *= corr; accO[1][r] *= corr; accO[2][r] *= corr;              \
      Pt[wq][lh * 4 + r][l15]      = __float2bfloat16(p0);                     \
      Pt[wq][lh * 4 + r][16 + l15] = __float2bfloat16(p1);                     \
      Pt[wq][lh * 4 + r][32 + l15] = __float2bfloat16(p2);                     \
      Pt[wq][lh * 4 + r][48 + l15] = __float2bfloat16(p3);                     \
    }                                                                          \
    _Pragma("unroll") for (int ks = 0; ks < 2; ks++) {                         \
      bfrag pa = *(const bfrag*)&Pt[wq][l15][ks * 32 + lh * 8];                \
      __builtin_amdgcn_s_setprio(1);                                           \
      _Pragma("unroll") for (int t = 0; t < 3; t++)                            \
        accO[t] = __builtin_amdgcn_mfma_f32_16x16x32_bf16(pa, vf[ks][t],       \
                                                          accO[t], 0, 0, 0);  \
      __builtin_amdgcn_s_setprio(0);                                           \
    }                                                                          \
  }

__global__ __launch_bounds__(256, 2) void attn_mfma(
    const bf16* __restrict__ qkv, const bf16* __restrict__ vt,
    const float* __restrict__ log_slopes, bf16* __restrict__ obuf) {
  __shared__ bf16 Pt[4][16][72];   // per-wave [16 q rows][64 keys + pad]

  const int tid = threadIdx.x;
  const int wq = tid >> 6;
  const int lane = tid & 63;
  const int l15 = lane & 15;
  const int lh = lane >> 4;

  // XCD-contiguous swizzle (bijective: 1024 = 8 * 128): blocks dispatched
  // round-robin across XCDs; id%8 picks the chunk so one XCD's 128 blocks
  // cover 8 whole (b,h) pairs -> K/V fetched once per XCD instead of 8x.
  const int id = blockIdx.x;
  const int w = (id & 7) * 128 + (id >> 3);
  const int qb = (w & 15) * AQT;
  const int h = (w >> 4) & 15;
  const int b = w >> 8;

  const float log2e = 1.4426950408889634f;
  const float qscale = 0.14433756729740643f * 1.4426950408889634f; // 1/sqrt(48)*log2e
  const float slope = __expf(log_slopes[h]) * log2e;
  const size_t rstride = 3 * DMODEL;

  const bf16* qptr = qkv + ((size_t)(b * SEQ + qb + wq * 16 + l15)) * rstride + h * HD;
  const bf16* kl = qkv + ((size_t)(b * SEQ + l15)) * rstride + DMODEL + h * HD + lh * 8;
  const bf16* vl = vt + ((size_t)((b * HNUM + h) * HD + l15)) * SEQ + lh * 8;

  // Q fragments: prescaled, zero for k-slice elements beyond d=48.
  bfrag aq[2];
#pragma unroll
  for (int ks = 0; ks < 2; ks++) {
    bfrag raw;
#pragma unroll
    for (int i = 0; i < 8; i++) raw[i] = 0;
    if (ks == 0 || lh < 2) raw = *(const bfrag*)(qptr + ks * 32 + lh * 8);
#pragma unroll
    for (int i = 0; i < 8; i++) {
      float f = __uint_as_float(((unsigned)(unsigned short)raw[i]) << 16) * qscale;
      raw[i] = (short)f2bf_raw(f);
    }
    aq[ks] = raw;
  }

  float m_[4], l_[4];
  f32x4 accO[3];
#pragma unroll
  for (int r = 0; r < 4; r++) { m_[r] = -1e30f; l_[r] = 0.f; }
#pragma unroll
  for (int t = 0; t < 3; t++) accO[t] = (f32x4)(0.f);

  // K register double-buffer, named sets (static indexing only).
  bfrag kA[2][4], kB[2][4];
#pragma unroll
  for (int ks = 0; ks < 2; ks++)
#pragma unroll
    for (int j = 0; j < 4; j++)
      kA[ks][j] = *(const bfrag*)(kl + (size_t)(j * 16) * rstride + ks * 32);

  for (int kb2 = 0; kb2 < SEQ; kb2 += 2 * AKT) {
    ATTN_TILE(kA, kB, kb2)
    ATTN_TILE(kB, kA, kb2 + AKT)
  }

  // epilogue: O / l -> obuf
#pragma unroll
  for (int r = 0; r < 4; r++) {
    const float inv = 1.0f / l_[r];
    bf16* op = obuf + ((size_t)(b * SEQ + qb + wq * 16 + lh * 4 + r)) * DMODEL + h * HD;
#pragma unroll
    for (int t = 0; t < 3; t++)
      op[t * 16 + l15] = __float2bfloat16(accO[t][r] * inv);
  }
}

// ---------------------------------------------------------------------------
// launcher
// ---------------------------------------------------------------------------
extern "C" void kernel_launch(void* const* d_in, const int* in_sizes, int n_in,
                              void* d_out, int out_size, void* d_ws, size_t ws_size,
                              hipStream_t stream) {
  const float* cls_tokens = (const float*)d_in[0];
  const float* cls_token  = (const float*)d_in[1];
  const float* log_slopes = (const float*)d_in[2];
  const float* Wqkv = (const float*)d_in[3];
  const float* Wo   = (const float*)d_in[4];
  const float* Wg   = (const float*)d_in[5];
  const float* Wu   = (const float*)d_in[6];
  const float* Wd   = (const float*)d_in[7];
  const float* ln1_w = (const float*)d_in[8];
  const float* ln1_b = (const float*)d_in[9];
  const float* ln2_w = (const float*)d_in[10];
  const float* ln2_b = (const float*)d_in[11];
  const float* fin_w = (const float*)d_in[12];
  const float* fin_b = (const float*)d_in[13];
  float* out = (float*)d_out;

  const size_t ROWS = (size_t)BATCH * SEQ;  // 4096
  char* wsb = (char*)d_ws;
  float* x    = (float*)(wsb);                       // 12,582,912 B
  bf16* qkvb  = (bf16*)(wsb + 12582912);             // 18,874,368 B
  bf16* hb    = (bf16*)(wsb + 31457280);             //  6,291,456 B
  bf16* ob    = (bf16*)(wsb + 37748736);             //  6,291,456 B
  bf16* gub   = (bf16*)(wsb + 44040192);             // 25,165,824 B
  bf16* wbf   = (bf16*)(wsb + 94371840);             // 18,874,368 B
  bf16* vtb   = (bf16*)(wsb + 113246208);            //  6,291,456 B -> 119.5 MB

  bf16* wqkv_b = wbf;
  bf16* wo_b   = wbf + 1769472;
  bf16* wg_b   = wbf + 2359296;
  bf16* wu_b   = wbf + 4718592;
  bf16* wd_b   = wbf + 7077888;

  {
    const size_t total = ROWS * DMODEL;
    concat_kernel<<<(int)((total + 255) / 256), 256, 0, stream>>>(cls_tokens, cls_token, x);
  }

  for (int l = 0; l < LNUM; l++) {
    convert_w_kernel<<<9216, 256, 0, stream>>>(
        Wqkv + (size_t)l * 3 * DMODEL * DMODEL, Wo + (size_t)l * DMODEL * DMODEL,
        Wg + (size_t)l * FFDIM * DMODEL, Wu + (size_t)l * FFDIM * DMODEL,
        Wd + (size_t)l * DMODEL * FFDIM, wbf);

    ln_kernel<bf16><<<(int)ROWS, 256, 0, stream>>>(
        x, hb, ln1_w + l * DMODEL, ln1_b + l * DMODEL, DMODEL, DMODEL);
    gemm_bf16<2><<<dim3(3 * DMODEL / BN, ROWS / BM), 256, 0, stream>>>(
        hb, wqkv_b, qkvb, (int)ROWS, 3 * DMODEL, DMODEL);
    transpose_v<<<dim3(SEQ / 64, HNUM, BATCH), 256, 0, stream>>>(qkvb, vtb);
    attn_mfma<<<dim3(SEQ / AQT * HNUM * BATCH), 256, 0, stream>>>(
        qkvb, vtb, log_slopes, ob);
    gemm_bf16_n64<1><<<dim3(DMODEL / 64, ROWS / BM), 256, 0, stream>>>(
        ob, wo_b, x, (int)ROWS, DMODEL, DMODEL);
    ln_kernel<bf16><<<(int)ROWS, 256, 0, stream>>>(
        x, hb, ln2_w + l * DMODEL, ln2_b + l * DMODEL, DMODEL, DMODEL);
    gemm_gateup<<<dim3(FFDIM / BN, ROWS / BM), 256, 0, stream>>>(
        hb, wg_b, wu_b, gub, (int)ROWS, FFDIM, DMODEL);
    gemm_bf16_n64<1><<<dim3(DMODEL / 64, ROWS / BM), 256, 0, stream>>>(
        gub, wd_b, x, (int)ROWS, DMODEL, FFDIM);
  }

  ln_kernel<float><<<BATCH, 256, 0, stream>>>(x, out, fin_w, fin_b,
                                              (size_t)SEQ * DMODEL, DMODEL);
}

// Round 2
// 1754.097 us; speedup vs baseline: 1.1537x; 1.1537x over previous
//
#include <hip/hip_runtime.h>
#include <hip/hip_bf16.h>

// Problem constants
#define LNUM 6
#define HNUM 16
#define DMODEL 768
#define FFDIM 3072
#define BATCH 4
#define NTOK 1023
#define SEQ 1024          // NTOK + 1
#define HD 48             // DMODEL / HNUM
#define EPS 1e-5f

typedef __hip_bfloat16 bf16;

__device__ __forceinline__ unsigned short f2bf_raw(float f) {
  bf16 h = __float2bfloat16(f);
  union { bf16 h; unsigned short s; } u; u.h = h; return u.s;
}

// DPP helpers: reduction across the 16 contiguous lanes of a DPP "row".
// quad_perm(1,0,3,2)=0xB1 (xor1), quad_perm(2,3,0,1)=0x4E (xor2),
// row_ror:4=0x124, row_ror:8=0x128.  (Proven correct+fast in round 1.)
template <int CTRL>
__device__ __forceinline__ float dppf(float x) {
  return __int_as_float(__builtin_amdgcn_update_dpp(
      0, __float_as_int(x), CTRL, 0xf, 0xf, true));
}
__device__ __forceinline__ float row_max16(float x) {
  x = fmaxf(x, dppf<0xB1>(x));
  x = fmaxf(x, dppf<0x4E>(x));
  x = fmaxf(x, dppf<0x124>(x));
  x = fmaxf(x, dppf<0x128>(x));
  return x;
}
__device__ __forceinline__ float row_sum16(float x) {
  x += dppf<0xB1>(x);
  x += dppf<0x4E>(x);
  x += dppf<0x124>(x);
  x += dppf<0x128>(x);
  return x;
}

// ---------------------------------------------------------------------------
// concat: x[b,s,:] = s==0 ? cls_token : cls_tokens[b,s-1,:]  (fp32 residual)
// ---------------------------------------------------------------------------
__global__ __launch_bounds__(256) void concat_kernel(
    const float* __restrict__ cls_tokens, const float* __restrict__ cls_token,
    float* __restrict__ x) {
  size_t i = (size_t)blockIdx.x * blockDim.x + threadIdx.x;
  const size_t total = (size_t)BATCH * SEQ * DMODEL;
  if (i >= total) return;
  int d = (int)(i % DMODEL);
  size_t bs = i / DMODEL;
  int s = (int)(bs % SEQ);
  int b = (int)(bs / SEQ);
  float v;
  if (s == 0) v = cls_token[d];
  else v = cls_tokens[((size_t)b * NTOK + (s - 1)) * DMODEL + d];
  x[i] = v;
}

// ---------------------------------------------------------------------------
// per-layer weight pack fp32 -> bf16 (Wqkv | Wo | Wg | Wu | Wd concatenated)
// ---------------------------------------------------------------------------
#define W_QKV4  442368
#define W_O4    147456
#define W_FF4   589824
__global__ __launch_bounds__(256) void convert_w_kernel(
    const float* __restrict__ wqkv, const float* __restrict__ wo,
    const float* __restrict__ wg, const float* __restrict__ wu,
    const float* __restrict__ wd, bf16* __restrict__ dst) {
  size_t i4 = (size_t)blockIdx.x * 256 + threadIdx.x;
  size_t off4 = i4;
  const float* src;
  if (off4 < W_QKV4) src = wqkv;
  else { off4 -= W_QKV4;
    if (off4 < W_O4) src = wo;
    else { off4 -= W_O4;
      if (off4 < W_FF4) src = wg;
      else { off4 -= W_FF4;
        if (off4 < W_FF4) src = wu;
        else { off4 -= W_FF4; src = wd; } } } }
  float4 v = ((const float4*)src)[off4];
  ushort4 o;
  o.x = f2bf_raw(v.x); o.y = f2bf_raw(v.y);
  o.z = f2bf_raw(v.z); o.w = f2bf_raw(v.w);
  ((ushort4*)dst)[i4] = o;
}

// ---------------------------------------------------------------------------
// layernorm: one 256-thread block per row of 768. OUT = float or bf16.
// ---------------------------------------------------------------------------
__device__ __forceinline__ void st_ln(float* p, float v) { *p = v; }
__device__ __forceinline__ void st_ln(bf16* p, float v) { *p = __float2bfloat16(v); }

template <typename OUT>
__global__ __launch_bounds__(256) void ln_kernel(
    const float* __restrict__ in, OUT* __restrict__ out,
    const float* __restrict__ w, const float* __restrict__ bias,
    size_t in_stride, size_t out_stride) {
  const int row = blockIdx.x;
  const int tid = threadIdx.x;
  const float* x = in + (size_t)row * in_stride;
  OUT* y = out + (size_t)row * out_stride;

  float v0 = x[tid], v1 = x[tid + 256], v2 = x[tid + 512];
  float s = v0 + v1 + v2;
  float sq = v0 * v0 + v1 * v1 + v2 * v2;

  __shared__ float s_sum[256];
  __shared__ float s_sq[256];
  s_sum[tid] = s;
  s_sq[tid] = sq;
  __syncthreads();
  for (int off = 128; off > 0; off >>= 1) {
    if (tid < off) {
      s_sum[tid] += s_sum[tid + off];
      s_sq[tid] += s_sq[tid + off];
    }
    __syncthreads();
  }
  const float inv_d = 1.0f / (float)DMODEL;
  float mean = s_sum[0] * inv_d;
  float var = s_sq[0] * inv_d - mean * mean;
  float rstd = rsqrtf(var + EPS);

  st_ln(y + tid,       (v0 - mean) * rstd * w[tid]       + bias[tid]);
  st_ln(y + tid + 256, (v1 - mean) * rstd * w[tid + 256] + bias[tid + 256]);
  st_ln(y + tid + 512, (v2 - mean) * rstd * w[tid + 512] + bias[tid + 512]);
}

// ---------------------------------------------------------------------------
// bf16 MFMA NT GEMM, double-buffered LDS pipeline. 128x128 tile, BK=32.
// CMODE: 0 = store fp32, 1 = accumulate fp32, 2 = store bf16.
// ---------------------------------------------------------------------------
#define BM 128
#define BN 128
#define BK 32

typedef __attribute__((ext_vector_type(8))) short bfrag;
typedef __attribute__((ext_vector_type(4))) float f32x4;

__device__ __forceinline__ void async_copy16(const void* g, void* l) {
  __builtin_amdgcn_global_load_lds(
      (const __attribute__((address_space(1))) void*)g,
      (__attribute__((address_space(3))) void*)l, 16, 0, 0);
}

template <int CMODE>
__global__ __launch_bounds__(256) void gemm_bf16(
    const bf16* __restrict__ A, const bf16* __restrict__ B,
    void* __restrict__ Cv, int M, int N, int K) {
  __shared__ bf16 As[2][BM][BK];  // 16 KB
  __shared__ bf16 Bs[2][BN][BK];  // 16 KB

  const int tid = threadIdx.x;
  const int wave = tid >> 6;
  const int lane = tid & 63;
  const int m0 = blockIdx.y * BM;
  const int n0 = blockIdx.x * BN;
  const int wm = (wave & 1) * 64;
  const int wn = (wave >> 1) * 64;

  f32x4 acc[4][4];
#pragma unroll
  for (int i = 0; i < 4; i++)
#pragma unroll
    for (int j = 0; j < 4; j++) acc[i][j] = (f32x4)(0.f);

  const int lrow = lane >> 2;
  const int lcol = (lane & 3) * 8;
  const bf16* Ag[2]; const bf16* Bg[2];
  void *AsB[2][2], *BsB[2][2];   // [buf][chunk]
#pragma unroll
  for (int j = 0; j < 2; j++) {
    int c = j * 4 + wave;
    Ag[j] = A + (size_t)(m0 + c * 16 + lrow) * K + lcol;
    Bg[j] = B + (size_t)(n0 + c * 16 + lrow) * K + lcol;
#pragma unroll
    for (int bf = 0; bf < 2; bf++) {
      AsB[bf][j] = (void*)&As[bf][c * 16][0];
      BsB[bf][j] = (void*)&Bs[bf][c * 16][0];
    }
  }

#pragma unroll
  for (int j = 0; j < 2; j++) {
    async_copy16(Ag[j], AsB[0][j]);
    async_copy16(Bg[j], BsB[0][j]);
  }

  const int fr = lane & 15;
  const int fk = (lane >> 4) * 8;
  const int nk = K / BK;

  for (int ki = 0; ki < nk; ki++) {
    const int cur = ki & 1;
    __syncthreads();
    if (ki + 1 < nk) {
      const int k0 = (ki + 1) * BK;
#pragma unroll
      for (int j = 0; j < 2; j++) {
        async_copy16(Ag[j] + k0, AsB[cur ^ 1][j]);
        async_copy16(Bg[j] + k0, BsB[cur ^ 1][j]);
      }
    }
    bfrag a[4], b[4];
#pragma unroll
    for (int i = 0; i < 4; i++) {
      a[i] = *(const bfrag*)&As[cur][wm + i * 16 + fr][fk];
      b[i] = *(const bfrag*)&Bs[cur][wn + i * 16 + fr][fk];
    }
#pragma unroll
    for (int i = 0; i < 4; i++)
#pragma unroll
      for (int j = 0; j < 4; j++)
        acc[i][j] = __builtin_amdgcn_mfma_f32_16x16x32_bf16(a[i], b[j], acc[i][j], 0, 0, 0);
  }

  const int ccol = lane & 15;
  const int crow = (lane >> 4) * 4;
#pragma unroll
  for (int i = 0; i < 4; i++) {
#pragma unroll
    for (int j = 0; j < 4; j++) {
#pragma unroll
      for (int r = 0; r < 4; r++) {
        const size_t gm = m0 + wm + i * 16 + crow + r;
        const size_t gn = n0 + wn + j * 16 + ccol;
        if (CMODE == 2) {
          ((bf16*)Cv)[gm * N + gn] = __float2bfloat16(acc[i][j][r]);
        } else if (CMODE == 1) {
          float* cp = (float*)Cv + gm * N + gn;
          *cp += acc[i][j][r];
        } else {
          ((float*)Cv)[gm * N + gn] = acc[i][j][r];
        }
      }
    }
  }
}

// ---------------------------------------------------------------------------
// 64x64-tile variant for N=768 GEMMs (wo, wd): grid 768 blocks -> 3 blocks/CU
// uniform (vs 384 blocks / 1.5 per CU with the old 128x64 tile).
// Waves 2x2, each owns a 32x32 subtile (acc[2][2]). Same proven staging
// pattern: 1 async_copy16 per thread per matrix, linear lane->LDS order.
// ---------------------------------------------------------------------------
template <int CMODE>
__global__ __launch_bounds__(256) void gemm_bf16_n64(
    const bf16* __restrict__ A, const bf16* __restrict__ B,
    void* __restrict__ Cv, int M, int N, int K) {
  __shared__ bf16 As[2][64][BK];  // 8 KB
  __shared__ bf16 Bs[2][64][BK];  // 8 KB

  const int tid = threadIdx.x;
  const int wave = tid >> 6;
  const int lane = tid & 63;
  const int m0 = blockIdx.y * 64;
  const int n0 = blockIdx.x * 64;
  const int wm = (wave & 1) * 32;
  const int wn = (wave >> 1) * 32;

  f32x4 acc[2][2];
#pragma unroll
  for (int i = 0; i < 2; i++)
#pragma unroll
    for (int j = 0; j < 2; j++) acc[i][j] = (f32x4)(0.f);

  const int srow = tid >> 2;        // 0..63
  const int scol = (tid & 3) * 8;   // 0,8,16,24
  const bf16* Ag = A + (size_t)(m0 + srow) * K + scol;
  const bf16* Bg = B + (size_t)(n0 + srow) * K + scol;
  void *AsB[2], *BsB[2];
#pragma unroll
  for (int bf = 0; bf < 2; bf++) {
    AsB[bf] = (void*)&As[bf][srow][scol];
    BsB[bf] = (void*)&Bs[bf][srow][scol];
  }

  async_copy16(Ag, AsB[0]);
  async_copy16(Bg, BsB[0]);

  const int fr = lane & 15;
  const int fk = (lane >> 4) * 8;
  const int nk = K / BK;

  for (int ki = 0; ki < nk; ki++) {
    const int cur = ki & 1;
    __syncthreads();
    if (ki + 1 < nk) {
      const int k0 = (ki + 1) * BK;
      async_copy16(Ag + k0, AsB[cur ^ 1]);
      async_copy16(Bg + k0, BsB[cur ^ 1]);
    }
    bfrag a[2], b[2];
#pragma unroll
    for (int i = 0; i < 2; i++)
      a[i] = *(const bfrag*)&As[cur][wm + i * 16 + fr][fk];
#pragma unroll
    for (int j = 0; j < 2; j++)
      b[j] = *(const bfrag*)&Bs[cur][wn + j * 16 + fr][fk];
#pragma unroll
    for (int i = 0; i < 2; i++)
#pragma unroll
      for (int j = 0; j < 2; j++)
        acc[i][j] = __builtin_amdgcn_mfma_f32_16x16x32_bf16(a[i], b[j], acc[i][j], 0, 0, 0);
  }

  const int ccol = lane & 15;
  const int crow = (lane >> 4) * 4;
#pragma unroll
  for (int i = 0; i < 2; i++) {
#pragma unroll
    for (int j = 0; j < 2; j++) {
#pragma unroll
      for (int r = 0; r < 4; r++) {
        const size_t gm = m0 + wm + i * 16 + crow + r;
        const size_t gn = n0 + wn + j * 16 + ccol;
        if (CMODE == 2) {
          ((bf16*)Cv)[gm * N + gn] = __float2bfloat16(acc[i][j][r]);
        } else if (CMODE == 1) {
          float* cp = (float*)Cv + gm * N + gn;
          *cp += acc[i][j][r];
        } else {
          ((float*)Cv)[gm * N + gn] = acc[i][j][r];
        }
      }
    }
  }
}

// ---------------------------------------------------------------------------
// Fused gate+up GEMM with silu epilogue (dbuf, 3 staged matrices).
// ---------------------------------------------------------------------------
__global__ __launch_bounds__(256) void gemm_gateup(
    const bf16* __restrict__ A, const bf16* __restrict__ Wg,
    const bf16* __restrict__ Wu, bf16* __restrict__ gu, int M, int N, int K) {
  __shared__ bf16 As[2][BM][BK];
  __shared__ bf16 Gs[2][BN][BK];
  __shared__ bf16 Us[2][BN][BK];

  const int tid = threadIdx.x;
  const int wave = tid >> 6;
  const int lane = tid & 63;
  const int m0 = blockIdx.y * BM;
  const int n0 = blockIdx.x * BN;
  const int wm = (wave & 1) * 64;
  const int wn = (wave >> 1) * 64;

  f32x4 accG[4][4], accU[4][4];
#pragma unroll
  for (int i = 0; i < 4; i++)
#pragma unroll
    for (int j = 0; j < 4; j++) { accG[i][j] = (f32x4)(0.f); accU[i][j] = (f32x4)(0.f); }

  const int lrow = lane >> 2;
  const int lcol = (lane & 3) * 8;
  const bf16 *Ag[2], *Gg[2], *Ug[2];
  void *AsB[2][2], *GsB[2][2], *UsB[2][2];
#pragma unroll
  for (int j = 0; j < 2; j++) {
    int c = j * 4 + wave;
    Ag[j] = A + (size_t)(m0 + c * 16 + lrow) * K + lcol;
    Gg[j] = Wg + (size_t)(n0 + c * 16 + lrow) * K + lcol;
    Ug[j] = Wu + (size_t)(n0 + c * 16 + lrow) * K + lcol;
#pragma unroll
    for (int bf = 0; bf < 2; bf++) {
      AsB[bf][j] = (void*)&As[bf][c * 16][0];
      GsB[bf][j] = (void*)&Gs[bf][c * 16][0];
      UsB[bf][j] = (void*)&Us[bf][c * 16][0];
    }
  }

#pragma unroll
  for (int j = 0; j < 2; j++) {
    async_copy16(Ag[j], AsB[0][j]);
    async_copy16(Gg[j], GsB[0][j]);
    async_copy16(Ug[j], UsB[0][j]);
  }

  const int fr = lane & 15;
  const int fk = (lane >> 4) * 8;
  const int nk = K / BK;

  for (int ki = 0; ki < nk; ki++) {
    const int cur = ki & 1;
    __syncthreads();
    if (ki + 1 < nk) {
      const int k0 = (ki + 1) * BK;
#pragma unroll
      for (int j = 0; j < 2; j++) {
        async_copy16(Ag[j] + k0, AsB[cur ^ 1][j]);
        async_copy16(Gg[j] + k0, GsB[cur ^ 1][j]);
        async_copy16(Ug[j] + k0, UsB[cur ^ 1][j]);
      }
    }
    bfrag a[4], g[4], u[4];
#pragma unroll
    for (int i = 0; i < 4; i++) {
      a[i] = *(const bfrag*)&As[cur][wm + i * 16 + fr][fk];
      g[i] = *(const bfrag*)&Gs[cur][wn + i * 16 + fr][fk];
      u[i] = *(const bfrag*)&Us[cur][wn + i * 16 + fr][fk];
    }
#pragma unroll
    for (int i = 0; i < 4; i++)
#pragma unroll
      for (int j = 0; j < 4; j++) {
        accG[i][j] = __builtin_amdgcn_mfma_f32_16x16x32_bf16(a[i], g[j], accG[i][j], 0, 0, 0);
        accU[i][j] = __builtin_amdgcn_mfma_f32_16x16x32_bf16(a[i], u[j], accU[i][j], 0, 0, 0);
      }
  }

  const int ccol = lane & 15;
  const int crow = (lane >> 4) * 4;
#pragma unroll
  for (int i = 0; i < 4; i++) {
#pragma unroll
    for (int j = 0; j < 4; j++) {
#pragma unroll
      for (int r = 0; r < 4; r++) {
        const size_t gm = m0 + wm + i * 16 + crow + r;
        const size_t gn = n0 + wn + j * 16 + ccol;
        const float gv = accG[i][j][r];
        const float uv = accU[i][j][r];
        const float res = gv / (1.0f + __expf(-gv)) * uv;
        gu[gm * N + gn] = __float2bfloat16(res);
      }
    }
  }
}

// ---------------------------------------------------------------------------
// V transpose pre-pass: vt[b][h][d][s] = qkv[b][s][2D + h*HD + d]
// ---------------------------------------------------------------------------
__global__ __launch_bounds__(256) void transpose_v(
    const bf16* __restrict__ qkv, bf16* __restrict__ vt) {
  __shared__ bf16 T[HD][64];
  const int tid = threadIdx.x;
  const int kb = blockIdx.x * 64;
  const int h = blockIdx.y;
  const int b = blockIdx.z;
  const size_t rstride = 3 * DMODEL;
  const bf16* vsrc = qkv + ((size_t)(b * SEQ + kb)) * rstride + 2 * DMODEL + h * HD;

  if (tid < 192) {
    int p = tid & 31, c = tid >> 5;   // 32 key-pairs x 6 d-chunks
    const bf16* v0 = vsrc + (size_t)(2 * p) * rstride + c * 8;
    uint4 r0 = *(const uint4*)v0;
    uint4 r1 = *(const uint4*)(v0 + rstride);
    const unsigned int* w0 = (const unsigned int*)&r0;
    const unsigned int* w1 = (const unsigned int*)&r1;
#pragma unroll
    for (int i = 0; i < 8; i++) {
      unsigned int lo = (i & 1) ? (w0[i >> 1] >> 16) : (w0[i >> 1] & 0xffffu);
      unsigned int hi = (i & 1) ? (w1[i >> 1] >> 16) : (w1[i >> 1] & 0xffffu);
      *(unsigned int*)&T[c * 8 + i][2 * p] = lo | (hi << 16);
    }
  }
  __syncthreads();
  for (int it = tid; it < HD * 8; it += 256) {
    int d = it >> 3, c = it & 7;
    *(uint4*)(vt + ((size_t)((b * HNUM + h) * HD + d)) * SEQ + kb + c * 8) =
        *(const uint4*)&T[d][c * 8];
  }
}

// ---------------------------------------------------------------------------
// MFMA flash attention, register-prefetched LDS staging (proven 87us
// structure from round 0), upgraded with the round-1-proven components:
//  - DPP 16-lane reductions (no ds_bpermute -> DS-pipe pressure ~halved)
//  - exp2 domain (scale & slope pre-multiplied by log2e; bare v_exp_f32)
//  - s_setprio(1) around both MFMA clusters (m191: +4-7% attn)
//  - bijective XCD-contiguous block swizzle (FETCH 58.7MB -> 9.8MB, r1)
// Barriers retained: they anchor the reg-prefetch -> publish pipeline that
// the barrier-free version lost to compiler load-sinking (r1 post-mortem).
// ---------------------------------------------------------------------------
#define AQT 64
#define AKT 64
#define ASTR 72

__global__ __launch_bounds__(256, 4) void attn_mfma(
    const bf16* __restrict__ qkv, const bf16* __restrict__ vt,
    const float* __restrict__ log_slopes, bf16* __restrict__ obuf) {
  __shared__ bf16 Qs[AQT][ASTR];
  __shared__ bf16 Ks[AKT][ASTR];
  __shared__ bf16 Vs[HD][ASTR];
  __shared__ bf16 Pt[AQT][ASTR];

  const int tid = threadIdx.x;
  const int wq = tid >> 6;
  const int lane = tid & 63;
  const int l15 = lane & 15;
  const int lh = lane >> 4;

  // XCD-contiguous swizzle (bijective: 1024 = 8 * 128): one XCD's 128
  // blocks cover 8 whole (b,h) pairs -> K/V fetched once per XCD.
  const int id = blockIdx.x;
  const int w = (id & 7) * 128 + (id >> 3);
  const int qb = (w & 15) * AQT;
  const int h = (w >> 4) & 15;
  const int b = w >> 8;

  const float c1 = 0.14433756729740643f * 1.4426950408889634f;  // scale*log2e
  const float slope2 = __expf(log_slopes[h]) * 1.4426950408889634f;
  const size_t rstride = 3 * DMODEL;
  const bf16* qbase = qkv + ((size_t)(b * SEQ + qb)) * rstride + h * HD;
  const bf16* kbase0 = qkv + ((size_t)b * SEQ) * rstride + DMODEL + h * HD;
  const bf16* vbase0 = vt + ((size_t)((b * HNUM + h) * HD)) * SEQ;

  // staging descriptors: 3 uint4/thread (384 K-entries, then 384 V-entries)
  bf16* ldst[3];
  size_t goff[3];
  bool isK[3];
#pragma unroll
  for (int j = 0; j < 3; j++) {
    int id2 = tid + j * 256;
    if (id2 < 384) {
      int r = id2 / 6, c = id2 - r * 6;
      ldst[j] = &Ks[r][c * 8];
      goff[j] = (size_t)r * rstride + c * 8;
      isK[j] = true;
    } else {
      id2 -= 384;
      int d = id2 >> 3, c = id2 & 7;
      ldst[j] = &Vs[d][c * 8];
      goff[j] = (size_t)d * SEQ + c * 8;
      isK[j] = false;
    }
  }

  // zero-pad d = 48..63 of Qs, Ks (stage loops never touch it)
  for (int it = tid; it < AQT * 2; it += 256) {
    int r = it >> 1, c = it & 1;
    *(uint4*)&Qs[r][48 + c * 8] = make_uint4(0, 0, 0, 0);
    *(uint4*)&Ks[r][48 + c * 8] = make_uint4(0, 0, 0, 0);
  }
  // stage Q
  for (int it = tid; it < AQT * 6; it += 256) {
    int r = it / 6, c = it - (it / 6) * 6;
    *(uint4*)&Qs[r][c * 8] = *(const uint4*)(qbase + (size_t)r * rstride + c * 8);
  }

  // prefetch tile 0
  uint4 pre[3];
#pragma unroll
  for (int j = 0; j < 3; j++)
    pre[j] = *(const uint4*)((isK[j] ? kbase0 : vbase0) + goff[j]);

  float m_[4], l_[4];
  f32x4 accO[3];
#pragma unroll
  for (int r = 0; r < 4; r++) { m_[r] = -1e30f; l_[r] = 0.f; }
#pragma unroll
  for (int t = 0; t < 3; t++) accO[t] = (f32x4)(0.f);

  for (int kb = 0; kb < SEQ; kb += AKT) {
    __syncthreads();  // prior compute done reading Ks/Vs (covers Q/pad on 1st)
    // publish prefetched tile
#pragma unroll
    for (int j = 0; j < 3; j++) *(uint4*)ldst[j] = pre[j];
    __syncthreads();
    // prefetch next tile (consumed after a full compute phase)
    if (kb + AKT < SEQ) {
      const bf16* kb1 = kbase0 + (size_t)(kb + AKT) * rstride;
      const bf16* vb1 = vbase0 + (kb + AKT);
#pragma unroll
      for (int j = 0; j < 3; j++)
        pre[j] = *(const uint4*)((isK[j] ? kb1 : vb1) + goff[j]);
    }

    // QK^T
    f32x4 accS[4];
#pragma unroll
    for (int j = 0; j < 4; j++) accS[j] = (f32x4)(0.f);
    __builtin_amdgcn_s_setprio(1);
#pragma unroll
    for (int ks = 0; ks < 2; ks++) {
      bfrag a = *(const bfrag*)&Qs[wq * 16 + l15][ks * 32 + lh * 8];
#pragma unroll
      for (int j = 0; j < 4; j++) {
        bfrag bk = *(const bfrag*)&Ks[j * 16 + l15][ks * 32 + lh * 8];
        accS[j] = __builtin_amdgcn_mfma_f32_16x16x32_bf16(a, bk, accS[j], 0, 0, 0);
      }
    }
    __builtin_amdgcn_s_setprio(0);

    // bias + online softmax (exp2 domain, DPP reductions);
    // C-layout: row(q) = lh*4 + r, col(key) = l15
    float ps[4][4];
#pragma unroll
    for (int r = 0; r < 4; r++) {
      const float fq = (float)(qb + wq * 16 + lh * 4 + r);
      float s[4];
#pragma unroll
      for (int j = 0; j < 4; j++) {
        const float fk = (float)(kb + j * 16 + l15);
        const float t = slope2 * fabsf(fq - fk);
        s[j] = fmaf(accS[j][r], c1, -t);
      }
      float mx = row_max16(fmaxf(fmaxf(s[0], s[1]), fmaxf(s[2], s[3])));
      const float mnew = fmaxf(m_[r], mx);
      const float corr = exp2f(m_[r] - mnew);
      float rs = 0.f;
#pragma unroll
      for (int j = 0; j < 4; j++) {
        ps[j][r] = exp2f(s[j] - mnew);
        rs += ps[j][r];
      }
      rs = row_sum16(rs);
      l_[r] = l_[r] * corr + rs;
      m_[r] = mnew;
#pragma unroll
      for (int t = 0; t < 3; t++) accO[t][r] *= corr;
    }

    // P -> per-wave LDS slice Pt[q][key]
#pragma unroll
    for (int j = 0; j < 4; j++)
#pragma unroll
      for (int r = 0; r < 4; r++)
        Pt[wq * 16 + lh * 4 + r][j * 16 + l15] = __float2bfloat16(ps[j][r]);

    // PV (wave-private Pt rows; in-wave lgkmcnt ordering suffices)
#pragma unroll
    for (int ks = 0; ks < 2; ks++) {
      bfrag pa = *(const bfrag*)&Pt[wq * 16 + l15][ks * 32 + lh * 8];
      __builtin_amdgcn_s_setprio(1);
#pragma unroll
      for (int t = 0; t < 3; t++) {
        bfrag vb = *(const bfrag*)&Vs[t * 16 + l15][ks * 32 + lh * 8];
        accO[t] = __builtin_amdgcn_mfma_f32_16x16x32_bf16(pa, vb, accO[t], 0, 0, 0);
      }
      __builtin_amdgcn_s_setprio(0);
    }
  }

  // epilogue: O / l -> obuf
#pragma unroll
  for (int r = 0; r < 4; r++) {
    const float inv = 1.0f / l_[r];
    bf16* op = obuf + ((size_t)(b * SEQ + qb + wq * 16 + lh * 4 + r)) * DMODEL + h * HD;
#pragma unroll
    for (int t = 0; t < 3; t++)
      op[t * 16 + l15] = __float2bfloat16(accO[t][r] * inv);
  }
}

// ---------------------------------------------------------------------------
// launcher
// ---------------------------------------------------------------------------
extern "C" void kernel_launch(void* const* d_in, const int* in_sizes, int n_in,
                              void* d_out, int out_size, void* d_ws, size_t ws_size,
                              hipStream_t stream) {
  const float* cls_tokens = (const float*)d_in[0];
  const float* cls_token  = (const float*)d_in[1];
  const float* log_slopes = (const float*)d_in[2];
  const float* Wqkv = (const float*)d_in[3];
  const float* Wo   = (const float*)d_in[4];
  const float* Wg   = (const float*)d_in[5];
  const float* Wu   = (const float*)d_in[6];
  const float* Wd   = (const float*)d_in[7];
  const float* ln1_w = (const float*)d_in[8];
  const float* ln1_b = (const float*)d_in[9];
  const float* ln2_w = (const float*)d_in[10];
  const float* ln2_b = (const float*)d_in[11];
  const float* fin_w = (const float*)d_in[12];
  const float* fin_b = (const float*)d_in[13];
  float* out = (float*)d_out;

  const size_t ROWS = (size_t)BATCH * SEQ;  // 4096
  char* wsb = (char*)d_ws;
  float* x    = (float*)(wsb);                       // 12,582,912 B
  bf16* qkvb  = (bf16*)(wsb + 12582912);             // 18,874,368 B
  bf16* hb    = (bf16*)(wsb + 31457280);             //  6,291,456 B
  bf16* ob    = (bf16*)(wsb + 37748736);             //  6,291,456 B
  bf16* gub   = (bf16*)(wsb + 44040192);             // 25,165,824 B
  bf16* wbf   = (bf16*)(wsb + 94371840);             // 18,874,368 B
  bf16* vtb   = (bf16*)(wsb + 113246208);            //  6,291,456 B -> 119.5 MB

  bf16* wqkv_b = wbf;
  bf16* wo_b   = wbf + 1769472;
  bf16* wg_b   = wbf + 2359296;
  bf16* wu_b   = wbf + 4718592;
  bf16* wd_b   = wbf + 7077888;

  {
    const size_t total = ROWS * DMODEL;
    concat_kernel<<<(int)((total + 255) / 256), 256, 0, stream>>>(cls_tokens, cls_token, x);
  }

  for (int l = 0; l < LNUM; l++) {
    convert_w_kernel<<<9216, 256, 0, stream>>>(
        Wqkv + (size_t)l * 3 * DMODEL * DMODEL, Wo + (size_t)l * DMODEL * DMODEL,
        Wg + (size_t)l * FFDIM * DMODEL, Wu + (size_t)l * FFDIM * DMODEL,
        Wd + (size_t)l * DMODEL * FFDIM, wbf);

    ln_kernel<bf16><<<(int)ROWS, 256, 0, stream>>>(
        x, hb, ln1_w + l * DMODEL, ln1_b + l * DMODEL, DMODEL, DMODEL);
    gemm_bf16<2><<<dim3(3 * DMODEL / BN, ROWS / BM), 256, 0, stream>>>(
        hb, wqkv_b, qkvb, (int)ROWS, 3 * DMODEL, DMODEL);
    transpose_v<<<dim3(SEQ / 64, HNUM, BATCH), 256, 0, stream>>>(qkvb, vtb);
    attn_mfma<<<dim3(SEQ / AQT * HNUM * BATCH), 256, 0, stream>>>(
        qkvb, vtb, log_slopes, ob);
    gemm_bf16_n64<1><<<dim3(DMODEL / 64, ROWS / 64), 256, 0, stream>>>(
        ob, wo_b, x, (int)ROWS, DMODEL, DMODEL);
    ln_kernel<bf16><<<(int)ROWS, 256, 0, stream>>>(
        x, hb, ln2_w + l * DMODEL, ln2_b + l * DMODEL, DMODEL, DMODEL);
    gemm_gateup<<<dim3(FFDIM / BN, ROWS / BM), 256, 0, stream>>>(
        hb, wg_b, wu_b, gub, (int)ROWS, FFDIM, DMODEL);
    gemm_bf16_n64<1><<<dim3(DMODEL / 64, ROWS / 64), 256, 0, stream>>>(
        gub, wd_b, x, (int)ROWS, DMODEL, FFDIM);
  }

  ln_kernel<float><<<BATCH, 256, 0, stream>>>(x, out, fin_w, fin_b,
                                              (size_t)SEQ * DMODEL, DMODEL);
}